// Round 10
// baseline (403.820 us; speedup 1.0000x reference)
//
#include <hip/hip_runtime.h>

typedef unsigned short ushort_t;
typedef __attribute__((ext_vector_type(4))) unsigned short ushort4_t;
typedef __attribute__((ext_vector_type(8))) short short8;
typedef __attribute__((ext_vector_type(4))) unsigned int uint4v;
typedef __attribute__((ext_vector_type(2))) float float2v;
typedef __attribute__((ext_vector_type(4))) float floatx4;
typedef __attribute__((ext_vector_type(16))) float floatx16;

#define B_ 4
#define C_ 256
#define R_ 256
#define M_ 40
#define NCLS 21
#define ROI_ 7
#define G_ 14
#define NROI_TOT 3072
#define PROPS_PER_IMG 768
#define POOL_PITCH 264   // ushorts per pool row (528 B, 16B-aligned) [R8 proven]
#define WCONV_ELEMS (256 * 2304)   // = 144 chunks * 4096
#define NKB 392                    // 12544 / 32 k-blocks for FC
#define WFC2_ELEMS (NKB * 32 * 32) // padded 32 classes, fragment-ordered
// ws layout (ushort offsets)
#define OFF_FWB   WCONV_ELEMS
#define OFF_CL3   (OFF_FWB + WFC2_ELEMS)
#define OFF_CL4   (OFF_CL3 + 4 * 64 * 64 * 256)
#define OFF_CL5   (OFF_CL4 + 4 * 32 * 32 * 256)

__device__ __forceinline__ ushort_t f2bf(float f) {
  unsigned u = __builtin_bit_cast(unsigned, f);
  u += 0x7fff + ((u >> 16) & 1);  // RNE
  return (ushort_t)(u >> 16);
}
__device__ __forceinline__ float bf2f(ushort_t h) {
  unsigned u = ((unsigned)h) << 16;
  return __builtin_bit_cast(float, u);
}
// two packed bf16 (one dword) -> float2 {low half, high half}
__device__ __forceinline__ float2v cvt2(unsigned u) {
  float2v r;
  r[0] = __builtin_bit_cast(float, u << 16);
  r[1] = __builtin_bit_cast(float, u & 0xffff0000u);
  return r;
}

// ---------------------------------------------------------------------------
// K0 (merged): blocks [0,512): conv_w -> bf16 chunk-major wr2[kk][co][i];
//   fc_w -> bf16 MFMA-A-fragment order fwb2[kb][cls32][kq][8] (cls>20 = 0);
//   blocks [512,960): feats fp32 NCHW -> bf16 NHWC;
//   blocks [960,972): IoU matching.
// ---------------------------------------------------------------------------
__global__ __launch_bounds__(256) void prep_kernel(
    const float* __restrict__ cw, const float* __restrict__ fw,
    const float* __restrict__ f3, const float* __restrict__ f4,
    const float* __restrict__ f5, const float* __restrict__ p3,
    const float* __restrict__ p4, const float* __restrict__ p5,
    const float* __restrict__ gt, ushort_t* __restrict__ wr,
    ushort_t* __restrict__ fwb, ushort_t* __restrict__ cl3,
    ushort_t* __restrict__ cl4, ushort_t* __restrict__ cl5,
    float* __restrict__ out) {
  __shared__ ushort_t tile[256 * 65];  // [c][x], pitch 65 -> 2-way max
  const int id = blockIdx.x;
  const int t = threadIdx.x;

  if (id < 512) {
    // ---- conv weights: chunk-major ----
    const int i0 = id * 256 + t;
    const int stride = 512 * 256;
    for (int idx = i0; idx < WCONV_ELEMS; idx += stride) {
      const int kk = idx >> 12;
      const int rem = idx & 4095;
      const int co = rem >> 4;
      const int i = rem & 15;
      const int k = kk * 16 + i;
      const int j = k >> 8;
      const int ci = k & 255;
      wr[idx] = f2bf(cw[(co * 256 + ci) * 9 + j]);
    }
    // ---- fc weights: A-fragment order, 32 padded class rows ----
    for (int idx = i0; idx < WFC2_ELEMS; idx += stride) {
      const int kb = idx >> 10;
      const int rem = idx & 1023;
      const int cls = rem >> 5;
      const int koff = rem & 31;
      fwb[idx] =
          (cls < NCLS) ? f2bf(fw[(size_t)cls * 12544 + kb * 32 + koff]) : 0;
    }
  } else if (id < 960) {
    // ---- features NCHW -> NHWC bf16 ----
    const int fid = id - 512;
    const float* in;
    ushort_t* outp;
    int b, y, W;
    if (fid < 256) { in = f3; outp = cl3; W = 64; b = fid >> 6; y = fid & 63; }
    else if (fid < 384) { in = f4; outp = cl4; W = 32; b = (fid - 256) >> 5; y = (fid - 256) & 31; }
    else { in = f5; outp = cl5; W = 16; b = (fid - 384) >> 4; y = (fid - 384) & 15; }

    for (int idx = t; idx < 256 * W; idx += 256) {
      const int c = idx / W;
      const int x = idx - c * W;
      tile[c * 65 + x] = f2bf(in[((size_t)(b * 256 + c) * W + y) * W + x]);
    }
    __syncthreads();
    ushort_t* orow = outp + ((size_t)(b * W + y) * W) * 256;
    for (int idx = t; idx < W * 64; idx += 256) {
      const int x = idx >> 6;
      const int c4 = (idx & 63) * 4;
      ushort4_t v;
      v[0] = tile[(c4 + 0) * 65 + x];
      v[1] = tile[(c4 + 1) * 65 + x];
      v[2] = tile[(c4 + 2) * 65 + x];
      v[3] = tile[(c4 + 3) * 65 + x];
      *(ushort4_t*)(orow + (size_t)x * 256 + c4) = v;
    }
  } else {
    // ---- matching ----
    const int gidx = (id - 960) * 256 + t;
    if (gidx >= NROI_TOT) return;
    const int b = gidx / PROPS_PER_IMG;
    const int i = gidx - b * PROPS_PER_IMG;
    const int lvl = i >> 8;
    const int r = i & 255;
    const float* prop =
        (lvl == 0 ? p3 : (lvl == 1 ? p4 : p5)) + (size_t)(b * R_ + r) * 4;
    const float px1 = prop[0], py1 = prop[1], px2 = prop[2], py2 = prop[3];
    const float a1 = (px2 - px1) * (py2 - py1);
    const float* gtb = gt + (size_t)b * M_ * 5;

    float best = -2.f;
    int bi = 0;
    for (int j = 0; j < M_; ++j) {
      const float gx1 = gtb[j * 5 + 0], gy1 = gtb[j * 5 + 1];
      const float gx2 = gtb[j * 5 + 2], gy2 = gtb[j * 5 + 3];
      const float cls = gtb[j * 5 + 4];
      const float tlx = fmaxf(px1, gx1), tly = fmaxf(py1, gy1);
      const float brx = fminf(px2, gx2), bry = fminf(py2, gy2);
      const float iw = fmaxf(brx - tlx, 0.f), ih = fmaxf(bry - tly, 0.f);
      const float inter = iw * ih;
      const float a2 = (gx2 - gx1) * (gy2 - gy1);
      const float iou = inter / ((a1 + a2) - inter);
      const float m = (cls != -1.0f) ? iou : -1.0f;
      if (m > best) { best = m; bi = j; }
    }
    float o0, o1, o2, o3, o4;
    if (best <= 0.4f) {
      o0 = o1 = o2 = o3 = o4 = -1.0f;
    } else if (best < 0.6f) {
      o0 = o1 = o2 = o3 = o4 = -1e8f;
    } else {
      o0 = gtb[bi * 5 + 0]; o1 = gtb[bi * 5 + 1]; o2 = gtb[bi * 5 + 2];
      o3 = gtb[bi * 5 + 3]; o4 = gtb[bi * 5 + 4];
    }
    float* od = out + (size_t)NROI_TOT * NCLS + (size_t)gidx * 5;
    od[0] = o0; od[1] = o1; od[2] = o2; od[3] = o3; od[4] = o4;
  }
}

// ---------------------------------------------------------------------------
// K1: fused roi-align -> barrier-free MFMA conv3x3 -> relu -> MFMA FC.
//     512 threads (8 waves) per block, 2 rois per block.
//     Conv tiling: wave = (co-group w&3 -> 64 co, roi w>>2) -> 2 A-frags x
//     2 B-frags = 4 MFMA/k-step, 4 acc (64 AGPR, 4 waves/SIMD kept).
//     Halves B LDS traffic vs co-only split (B shared per roi, not 8x).
// ---------------------------------------------------------------------------
__global__ __launch_bounds__(512, 4) void cls_head_kernel(
    const ushort_t* __restrict__ cl3, const ushort_t* __restrict__ cl4,
    const ushort_t* __restrict__ cl5, const float* __restrict__ p3,
    const float* __restrict__ p4, const float* __restrict__ p5,
    const ushort_t* __restrict__ wr, const float* __restrict__ conv_b,
    const ushort_t* __restrict__ fwb, const float* __restrict__ fc_b,
    float* __restrict__ out) {
  __shared__ __align__(16) ushort_t s_pool[2 * 50 * POOL_PITCH];  // 52.8 KB
  __shared__ int s_iy0[28], s_iy1[28], s_ix0[28], s_ix1[28];
  __shared__ float s_ly[28], s_lx[28], s_vy[28], s_vx[28];
  __shared__ float s_fcred[NCLS * 2 * 8];  // [class(21)][roi(2)][wave(8)]

  const int bid = blockIdx.x;
  const int t = threadIdx.x;

  // XCD-locality swizzle: blocks with (bid&7)>>1 == img handle image img.
  const int img = (bid & 7) >> 1;
  const int pair = (bid >> 3) * 2 + (bid & 1);  // 0..383 within image
  const int rid0 = img * PROPS_PER_IMG + pair * 2;

  // per-roi metadata
  const ushort_t* clb_[2];
  int W_[2];
  const float* prop_[2];
#pragma unroll
  for (int rr = 0; rr < 2; ++rr) {
    const int rid = rid0 + rr;
    const int b = rid / PROPS_PER_IMG;
    const int rem = rid - b * PROPS_PER_IMG;
    const int lvl = rem >> 8;
    const int r = rem & 255;
    const ushort_t* base;
    const float* pp;
    int Wl;
    if (lvl == 0) { base = cl3; pp = p3; Wl = 64; }
    else if (lvl == 1) { base = cl4; pp = p4; Wl = 32; }
    else { base = cl5; pp = p5; Wl = 16; }
    clb_[rr] = base + (size_t)b * Wl * Wl * 256;
    W_[rr] = Wl;
    prop_[rr] = pp + (size_t)(b * R_ + r) * 4;
  }

  // zero rows 49/99 (im2col zero-row per roi); cols 0..255 read by conv
  if (t < 256) {
    s_pool[49 * POOL_PITCH + t] = 0;
    s_pool[99 * POOL_PITCH + t] = 0;
  }

  // ---- axis tables for both rois ------------------------------------------
  if (t < 56) {
    const int rr = t / 28;
    const int tt = t - rr * 28;
    const float* prop = prop_[rr];
    const int H = W_[rr];
    const float scale = 1.0f / (float)(H == 64 ? 8 : (H == 32 ? 16 : 32));
    const float bx1 = prop[0], by1 = prop[1], bx2 = prop[2], by2 = prop[3];
    const float ax = bx1 * scale - 0.5f;
    const float ay = by1 * scale - 0.5f;
    const float rw = bx2 * scale - 0.5f - ax;
    const float rh = by2 * scale - 0.5f - ay;
    const int i = (tt < G_) ? tt : (tt - G_);
    const float frac = ((float)i + 0.5f) / (float)G_;
    const int o = rr * G_ + i;
    if (tt < G_) {
      float yy = ay + frac * rh;
      float v = (yy >= -1.0f && yy <= (float)H) ? 1.0f : 0.0f;
      float y = fminf(fmaxf(yy, 0.0f), (float)(H - 1));
      float y0f = floorf(y);
      int y0 = (int)y0f;
      s_iy0[o] = y0;
      s_iy1[o] = min(y0 + 1, H - 1);
      s_ly[o] = y - y0f;
      s_vy[o] = v;
    } else {
      float xx = ax + frac * rw;
      float v = (xx >= -1.0f && xx <= (float)H) ? 1.0f : 0.0f;
      float x = fminf(fmaxf(xx, 0.0f), (float)(H - 1));
      float x0f = floorf(x);
      int x0 = (int)x0f;
      s_ix0[o] = x0;
      s_ix1[o] = min(x0 + 1, H - 1);
      s_lx[o] = x - x0f;
      s_vx[o] = v;
    }
  }
  __syncthreads();

  const int l = t & 63;
  const int w = t >> 6;  // 0..7

  // ---- roi-align: half-wave per cell, lane = 8 channels, packed f32 math --
  {
    const int hw = l >> 5;        // which cell of the pair
    const int c8 = (l & 31) * 8;  // channel offset
    for (int cb = w * 2; cb < 98; cb += 16) {
      const int cell = cb + hw;
      if (cell >= 98) continue;
      const int rr = (cell >= 49) ? 1 : 0;
      const int pos = cell - rr * 49;
      const int py = pos / 7, px = pos - (pos / 7) * 7;
      const ushort_t* clb = clb_[rr];
      const int W = W_[rr];
      float2v a01 = {0.f, 0.f}, a23 = {0.f, 0.f};
      float2v a45 = {0.f, 0.f}, a67 = {0.f, 0.f};
#pragma unroll
      for (int sy = 0; sy < 2; ++sy) {
        const int gy = rr * G_ + 2 * py + sy;
        const int iy0 = s_iy0[gy], iy1 = s_iy1[gy];
        const float ly = s_ly[gy], vy = s_vy[gy];
        const float hy = 1.0f - ly;
#pragma unroll
        for (int sx = 0; sx < 2; ++sx) {
          const int gx = rr * G_ + 2 * px + sx;
          const int ix0 = s_ix0[gx], ix1 = s_ix1[gx];
          const float lx = s_lx[gx], vx = s_vx[gx];
          const float hx = 1.0f - lx;
          const float vv = vy * vx;
          const float w00 = vv * hy * hx, w01 = vv * hy * lx;
          const float w10 = vv * ly * hx, w11 = vv * ly * lx;
          const uint4v u00 = *(const uint4v*)(clb + ((size_t)(iy0 * W + ix0) * 256 + c8));
          const uint4v u01 = *(const uint4v*)(clb + ((size_t)(iy0 * W + ix1) * 256 + c8));
          const uint4v u10 = *(const uint4v*)(clb + ((size_t)(iy1 * W + ix0) * 256 + c8));
          const uint4v u11 = *(const uint4v*)(clb + ((size_t)(iy1 * W + ix1) * 256 + c8));
          a01 += cvt2(u00[0]) * w00 + cvt2(u01[0]) * w01 +
                 cvt2(u10[0]) * w10 + cvt2(u11[0]) * w11;
          a23 += cvt2(u00[1]) * w00 + cvt2(u01[1]) * w01 +
                 cvt2(u10[1]) * w10 + cvt2(u11[1]) * w11;
          a45 += cvt2(u00[2]) * w00 + cvt2(u01[2]) * w01 +
                 cvt2(u10[2]) * w10 + cvt2(u11[2]) * w11;
          a67 += cvt2(u00[3]) * w00 + cvt2(u01[3]) * w01 +
                 cvt2(u10[3]) * w10 + cvt2(u11[3]) * w11;
        }
      }
      short8 pv;
      pv[0] = (short)f2bf(a01[0] * 0.25f);
      pv[1] = (short)f2bf(a01[1] * 0.25f);
      pv[2] = (short)f2bf(a23[0] * 0.25f);
      pv[3] = (short)f2bf(a23[1] * 0.25f);
      pv[4] = (short)f2bf(a45[0] * 0.25f);
      pv[5] = (short)f2bf(a45[1] * 0.25f);
      pv[6] = (short)f2bf(a67[0] * 0.25f);
      pv[7] = (short)f2bf(a67[1] * 0.25f);
      *(short8*)&s_pool[(rr * 50 + pos) * POOL_PITCH + c8] = pv;
    }
  }
  __syncthreads();  // pool + zero rows visible to all waves

  // ---- MFMA conv: wave = (co-group, roi); 2 A-frags x 2 B-frags -----------
  const int ml = l & 31;
  const int quad = l >> 5;
  const int cog = w & 3;        // 4 co-groups x 64
  const int posg = w >> 2;      // roi 0/1
  const int co_base = cog * 64;

  const int pA = ml;
  const int pB = ml + 32;
  const int pyA = pA / 7, pxA = pA % 7;
  const int pyB = pB / 7, pxB = pB % 7;

  floatx16 acc[4];  // [af*2+bf]: af = co frag, bf = pos frag
#pragma unroll
  for (int a = 0; a < 4; ++a)
#pragma unroll
    for (int i = 0; i < 16; ++i) acc[a][i] = 0.f;

  const ushort_t* a0p = wr + (co_base + ml) * 16 + quad * 8;
  const ushort_t* a1p = a0p + 32 * 16;
  const int roff = posg * 50;

  int kk = 0;
  for (int j = 0; j < 9; ++j) {
    const int dy = j / 3 - 1, dx = j % 3 - 1;
    int bnA, bnB;
    {
      const int ry = pyA + dy, rx = pxA + dx;
      const bool ok = (ry >= 0) & (ry < 7) & (rx >= 0) & (rx < 7);
      bnA = ok ? ry * 7 + rx : 49;
    }
    {
      const int ry = pyB + dy, rx = pxB + dx;
      const bool ok = (pB < 49) & (ry >= 0) & (ry < 7) & (rx >= 0) & (rx < 7);
      bnB = ok ? ry * 7 + rx : 49;
    }
    const int row0 = roff + bnA, row1 = roff + bnB;

#pragma unroll 4
    for (int kc = 0; kc < 16; ++kc, ++kk) {
      const short8 a0 = *(const short8*)(a0p + kk * 4096);
      const short8 a1 = *(const short8*)(a1p + kk * 4096);
      const int cof = kc * 16 + quad * 8;
      const short8 b0 = *(const short8*)&s_pool[row0 * POOL_PITCH + cof];
      const short8 b1 = *(const short8*)&s_pool[row1 * POOL_PITCH + cof];
      acc[0] = __builtin_amdgcn_mfma_f32_32x32x16_bf16(a0, b0, acc[0], 0, 0, 0);
      acc[1] = __builtin_amdgcn_mfma_f32_32x32x16_bf16(a0, b1, acc[1], 0, 0, 0);
      acc[2] = __builtin_amdgcn_mfma_f32_32x32x16_bf16(a1, b0, acc[2], 0, 0, 0);
      acc[3] = __builtin_amdgcn_mfma_f32_32x32x16_bf16(a1, b1, acc[3], 0, 0, 0);
    }
  }
  __syncthreads();  // all pool reads done before h overwrites it

  // ---- epilogue: bias + relu -> h in LDS (fc-k order: [rr][co*49+pos]) ----
  ushort_t* h_lds = s_pool;
  {
    const int hoff = posg * 12544;
#pragma unroll
    for (int af = 0; af < 2; ++af) {
#pragma unroll
      for (int reg = 0; reg < 16; ++reg) {
        const int co = co_base + af * 32 + (reg & 3) + 8 * (reg >> 2) + 4 * quad;
        const float cb = conv_b[co];
        const int base = hoff + co * 49;
        h_lds[base + pA] = f2bf(fmaxf(acc[af * 2 + 0][reg] + cb, 0.f));
        if (pB < 49) {
          h_lds[base + pB] = f2bf(fmaxf(acc[af * 2 + 1][reg] + cb, 0.f));
        }
      }
    }
  }
  __syncthreads();

  // ---- FC(12544 -> 21) via MFMA 16x16x32, K-split across 8 waves ----------
  // A from fwb2 fragment order (coalesced 1 KB/wave); B cols 0/1 = roi 0/1.
  {
    const int n = l & 15;        // C/D col; valid cols 0,1
    const int kq = l >> 4;       // 0..3
    const ushort_t* ap0 = fwb + (n * 4 + kq) * 8;
    const ushort_t* ap1 = ap0 + 512;
    const ushort_t* bp = h_lds + (size_t)(l & 1) * 12544 + kq * 8;
    const int kb0 = w * 49;

    floatx4 fa0, fa1;
#pragma unroll
    for (int i = 0; i < 4; ++i) { fa0[i] = 0.f; fa1[i] = 0.f; }

    for (int it = 0; it < 49; ++it) {
      const int kb = kb0 + it;
      const short8 av0 = *(const short8*)(ap0 + kb * 1024);
      const short8 av1 = *(const short8*)(ap1 + kb * 1024);
      const short8 bv = *(const short8*)(bp + kb * 32);
      fa0 = __builtin_amdgcn_mfma_f32_16x16x32_bf16(av0, bv, fa0, 0, 0, 0);
      fa1 = __builtin_amdgcn_mfma_f32_16x16x32_bf16(av1, bv, fa1, 0, 0, 0);
    }
    // C/D layout: col = l&15, row = (l>>4)*4 + reg
    if (n < 2) {
      const int m4 = kq * 4;
#pragma unroll
      for (int reg = 0; reg < 4; ++reg) {
        const int cls0 = m4 + reg;
        const int cls1 = 16 + m4 + reg;
        s_fcred[(cls0 * 2 + n) * 8 + w] = fa0[reg];
        if (cls1 < NCLS) s_fcred[(cls1 * 2 + n) * 8 + w] = fa1[reg];
      }
    }
  }
  __syncthreads();
  if (t < 2 * NCLS) {
    const int cls = t >> 1;
    const int rr = t & 1;
    const float* pr = &s_fcred[(cls * 2 + rr) * 8];
    float s = pr[0] + pr[1] + pr[2] + pr[3] + pr[4] + pr[5] + pr[6] + pr[7];
    out[(size_t)(rid0 + rr) * NCLS + cls] = s + fc_b[cls];
  }
}

extern "C" void kernel_launch(void* const* d_in, const int* in_sizes, int n_in,
                              void* d_out, int out_size, void* d_ws,
                              size_t ws_size, hipStream_t stream) {
  const float* f3 = (const float*)d_in[0];
  const float* f4 = (const float*)d_in[1];
  const float* f5 = (const float*)d_in[2];
  const float* p3 = (const float*)d_in[3];
  const float* p4 = (const float*)d_in[4];
  const float* p5 = (const float*)d_in[5];
  const float* gt = (const float*)d_in[6];
  const float* cw = (const float*)d_in[7];
  const float* cb = (const float*)d_in[8];
  const float* fw = (const float*)d_in[9];
  const float* fb = (const float*)d_in[10];
  float* out = (float*)d_out;

  ushort_t* wsp = (ushort_t*)d_ws;
  ushort_t* wr = wsp;
  ushort_t* fwb = wsp + OFF_FWB;
  ushort_t* cl3 = wsp + OFF_CL3;
  ushort_t* cl4 = wsp + OFF_CL4;
  ushort_t* cl5 = wsp + OFF_CL5;

  prep_kernel<<<972, 256, 0, stream>>>(cw, fw, f3, f4, f5, p3, p4, p5, gt, wr,
                                       fwb, cl3, cl4, cl5, out);
  cls_head_kernel<<<NROI_TOT / 2, 512, 0, stream>>>(cl3, cl4, cl5, p3, p4, p5,
                                                    wr, cb, fwb, fb, out);
}

// Round 11
// 356.994 us; speedup vs baseline: 1.1312x; 1.1312x over previous
//
#include <hip/hip_runtime.h>

typedef unsigned short ushort_t;
typedef __attribute__((ext_vector_type(4))) unsigned short ushort4_t;
typedef __attribute__((ext_vector_type(8))) short short8;
typedef __attribute__((ext_vector_type(4))) unsigned int uint4v;
typedef __attribute__((ext_vector_type(2))) float float2v;
typedef __attribute__((ext_vector_type(4))) float floatx4;
typedef __attribute__((ext_vector_type(16))) float floatx16;

#define B_ 4
#define C_ 256
#define R_ 256
#define M_ 40
#define NCLS 21
#define ROI_ 7
#define G_ 14
#define NROI_TOT 3072
#define PROPS_PER_IMG 768
#define POOL_PITCH 264   // ushorts per pool row (528 B, 16B-aligned) [R8 proven best]
#define WCONV_ELEMS (256 * 2304)   // = 144 chunks * 4096
#define NKB 392                    // 12544 / 32 k-blocks for FC
#define WFC2_ELEMS (NKB * 32 * 32) // padded 32 classes, fragment-ordered
// ws layout (ushort offsets)
#define OFF_FWB   WCONV_ELEMS
#define OFF_CL3   (OFF_FWB + WFC2_ELEMS)
#define OFF_CL4   (OFF_CL3 + 4 * 64 * 64 * 256)
#define OFF_CL5   (OFF_CL4 + 4 * 32 * 32 * 256)

__device__ __forceinline__ ushort_t f2bf(float f) {
  unsigned u = __builtin_bit_cast(unsigned, f);
  u += 0x7fff + ((u >> 16) & 1);  // RNE
  return (ushort_t)(u >> 16);
}
__device__ __forceinline__ float bf2f(ushort_t h) {
  unsigned u = ((unsigned)h) << 16;
  return __builtin_bit_cast(float, u);
}
// two packed bf16 (one dword) -> float2 {low half, high half}
__device__ __forceinline__ float2v cvt2(unsigned u) {
  float2v r;
  r[0] = __builtin_bit_cast(float, u << 16);
  r[1] = __builtin_bit_cast(float, u & 0xffff0000u);
  return r;
}

// ---------------------------------------------------------------------------
// K0 (merged): blocks [0,512): conv_w -> bf16 chunk-major wr2[kk][co][i];
//   fc_w -> bf16 MFMA-A-fragment order fwb2[kb][cls32][kq][8] (cls>20 = 0);
//   blocks [512,960): feats fp32 NCHW -> bf16 NHWC (conflict-free transpose);
//   blocks [960,972): IoU matching.
// ---------------------------------------------------------------------------
__global__ __launch_bounds__(256) void prep_kernel(
    const float* __restrict__ cw, const float* __restrict__ fw,
    const float* __restrict__ f3, const float* __restrict__ f4,
    const float* __restrict__ f5, const float* __restrict__ p3,
    const float* __restrict__ p4, const float* __restrict__ p5,
    const float* __restrict__ gt, ushort_t* __restrict__ wr,
    ushort_t* __restrict__ fwb, ushort_t* __restrict__ cl3,
    ushort_t* __restrict__ cl4, ushort_t* __restrict__ cl5,
    float* __restrict__ out) {
  __shared__ ushort_t tile[256 * 65];  // [c][x], pitch 65 -> 2-way max (free)
  const int id = blockIdx.x;
  const int t = threadIdx.x;

  if (id < 512) {
    // ---- conv weights: chunk-major ----
    const int i0 = id * 256 + t;
    const int stride = 512 * 256;
    for (int idx = i0; idx < WCONV_ELEMS; idx += stride) {
      const int kk = idx >> 12;
      const int rem = idx & 4095;
      const int co = rem >> 4;
      const int i = rem & 15;
      const int k = kk * 16 + i;
      const int j = k >> 8;
      const int ci = k & 255;
      wr[idx] = f2bf(cw[(co * 256 + ci) * 9 + j]);
    }
    // ---- fc weights: A-fragment order, 32 padded class rows ----
    for (int idx = i0; idx < WFC2_ELEMS; idx += stride) {
      const int kb = idx >> 10;
      const int rem = idx & 1023;
      const int cls = rem >> 5;
      const int koff = rem & 31;
      fwb[idx] =
          (cls < NCLS) ? f2bf(fw[(size_t)cls * 12544 + kb * 32 + koff]) : 0;
    }
  } else if (id < 960) {
    // ---- features NCHW -> NHWC bf16 ----
    const int fid = id - 512;
    const float* in;
    ushort_t* outp;
    int b, y, W;
    if (fid < 256) { in = f3; outp = cl3; W = 64; b = fid >> 6; y = fid & 63; }
    else if (fid < 384) { in = f4; outp = cl4; W = 32; b = (fid - 256) >> 5; y = (fid - 256) & 31; }
    else { in = f5; outp = cl5; W = 16; b = (fid - 384) >> 4; y = (fid - 384) & 15; }

    for (int idx = t; idx < 256 * W; idx += 256) {
      const int c = idx / W;
      const int x = idx - c * W;
      tile[c * 65 + x] = f2bf(in[((size_t)(b * 256 + c) * W + y) * W + x]);
    }
    __syncthreads();
    ushort_t* orow = outp + ((size_t)(b * W + y) * W) * 256;
    for (int idx = t; idx < W * 64; idx += 256) {
      const int x = idx >> 6;
      const int c4 = (idx & 63) * 4;
      ushort4_t v;
      v[0] = tile[(c4 + 0) * 65 + x];
      v[1] = tile[(c4 + 1) * 65 + x];
      v[2] = tile[(c4 + 2) * 65 + x];
      v[3] = tile[(c4 + 3) * 65 + x];
      *(ushort4_t*)(orow + (size_t)x * 256 + c4) = v;
    }
  } else {
    // ---- matching ----
    const int gidx = (id - 960) * 256 + t;
    if (gidx >= NROI_TOT) return;
    const int b = gidx / PROPS_PER_IMG;
    const int i = gidx - b * PROPS_PER_IMG;
    const int lvl = i >> 8;
    const int r = i & 255;
    const float* prop =
        (lvl == 0 ? p3 : (lvl == 1 ? p4 : p5)) + (size_t)(b * R_ + r) * 4;
    const float px1 = prop[0], py1 = prop[1], px2 = prop[2], py2 = prop[3];
    const float a1 = (px2 - px1) * (py2 - py1);
    const float* gtb = gt + (size_t)b * M_ * 5;

    float best = -2.f;
    int bi = 0;
    for (int j = 0; j < M_; ++j) {
      const float gx1 = gtb[j * 5 + 0], gy1 = gtb[j * 5 + 1];
      const float gx2 = gtb[j * 5 + 2], gy2 = gtb[j * 5 + 3];
      const float cls = gtb[j * 5 + 4];
      const float tlx = fmaxf(px1, gx1), tly = fmaxf(py1, gy1);
      const float brx = fminf(px2, gx2), bry = fminf(py2, gy2);
      const float iw = fmaxf(brx - tlx, 0.f), ih = fmaxf(bry - tly, 0.f);
      const float inter = iw * ih;
      const float a2 = (gx2 - gx1) * (gy2 - gy1);
      const float iou = inter / ((a1 + a2) - inter);
      const float m = (cls != -1.0f) ? iou : -1.0f;
      if (m > best) { best = m; bi = j; }
    }
    float o0, o1, o2, o3, o4;
    if (best <= 0.4f) {
      o0 = o1 = o2 = o3 = o4 = -1.0f;
    } else if (best < 0.6f) {
      o0 = o1 = o2 = o3 = o4 = -1e8f;
    } else {
      o0 = gtb[bi * 5 + 0]; o1 = gtb[bi * 5 + 1]; o2 = gtb[bi * 5 + 2];
      o3 = gtb[bi * 5 + 3]; o4 = gtb[bi * 5 + 4];
    }
    float* od = out + (size_t)NROI_TOT * NCLS + (size_t)gidx * 5;
    od[0] = o0; od[1] = o1; od[2] = o2; od[3] = o3; od[4] = o4;
  }
}

// ---------------------------------------------------------------------------
// K1: fused roi-align -> barrier-free MFMA conv3x3 -> relu -> MFMA FC.
//     512 threads (8 waves) per block, 2 rois per block.
//     Conv tiling = R8 proven best: wave = 32 co x 4 pos-tiles (2 rois),
//     1 A global stream : 4 B LDS b128 reads : 4 MFMA per k-step.
// ---------------------------------------------------------------------------
__global__ __launch_bounds__(512, 4) void cls_head_kernel(
    const ushort_t* __restrict__ cl3, const ushort_t* __restrict__ cl4,
    const ushort_t* __restrict__ cl5, const float* __restrict__ p3,
    const float* __restrict__ p4, const float* __restrict__ p5,
    const ushort_t* __restrict__ wr, const float* __restrict__ conv_b,
    const ushort_t* __restrict__ fwb, const float* __restrict__ fc_b,
    float* __restrict__ out) {
  __shared__ __align__(16) ushort_t s_pool[2 * 50 * POOL_PITCH];  // 52.8 KB
  __shared__ int s_iy0[28], s_iy1[28], s_ix0[28], s_ix1[28];
  __shared__ float s_ly[28], s_lx[28], s_vy[28], s_vx[28];
  __shared__ float s_fcred[NCLS * 2 * 8];  // [class(21)][roi(2)][wave(8)]

  const int bid = blockIdx.x;
  const int t = threadIdx.x;

  // XCD-locality swizzle: blocks with (bid&7)>>1 == img handle image img.
  const int img = (bid & 7) >> 1;
  const int pair = (bid >> 3) * 2 + (bid & 1);  // 0..383 within image
  const int rid0 = img * PROPS_PER_IMG + pair * 2;

  // per-roi metadata
  const ushort_t* clb_[2];
  int W_[2];
  const float* prop_[2];
#pragma unroll
  for (int rr = 0; rr < 2; ++rr) {
    const int rid = rid0 + rr;
    const int b = rid / PROPS_PER_IMG;
    const int rem = rid - b * PROPS_PER_IMG;
    const int lvl = rem >> 8;
    const int r = rem & 255;
    const ushort_t* base;
    const float* pp;
    int Wl;
    if (lvl == 0) { base = cl3; pp = p3; Wl = 64; }
    else if (lvl == 1) { base = cl4; pp = p4; Wl = 32; }
    else { base = cl5; pp = p5; Wl = 16; }
    clb_[rr] = base + (size_t)b * Wl * Wl * 256;
    W_[rr] = Wl;
    prop_[rr] = pp + (size_t)(b * R_ + r) * 4;
  }

  // zero rows 49/99 (im2col zero-row per roi); cols 0..255 read by conv
  if (t < 256) {
    s_pool[49 * POOL_PITCH + t] = 0;
    s_pool[99 * POOL_PITCH + t] = 0;
  }

  // ---- axis tables for both rois ------------------------------------------
  if (t < 56) {
    const int rr = t / 28;
    const int tt = t - rr * 28;
    const float* prop = prop_[rr];
    const int H = W_[rr];
    const float scale = 1.0f / (float)(H == 64 ? 8 : (H == 32 ? 16 : 32));
    const float bx1 = prop[0], by1 = prop[1], bx2 = prop[2], by2 = prop[3];
    const float ax = bx1 * scale - 0.5f;
    const float ay = by1 * scale - 0.5f;
    const float rw = bx2 * scale - 0.5f - ax;
    const float rh = by2 * scale - 0.5f - ay;
    const int i = (tt < G_) ? tt : (tt - G_);
    const float frac = ((float)i + 0.5f) / (float)G_;
    const int o = rr * G_ + i;
    if (tt < G_) {
      float yy = ay + frac * rh;
      float v = (yy >= -1.0f && yy <= (float)H) ? 1.0f : 0.0f;
      float y = fminf(fmaxf(yy, 0.0f), (float)(H - 1));
      float y0f = floorf(y);
      int y0 = (int)y0f;
      s_iy0[o] = y0;
      s_iy1[o] = min(y0 + 1, H - 1);
      s_ly[o] = y - y0f;
      s_vy[o] = v;
    } else {
      float xx = ax + frac * rw;
      float v = (xx >= -1.0f && xx <= (float)H) ? 1.0f : 0.0f;
      float x = fminf(fmaxf(xx, 0.0f), (float)(H - 1));
      float x0f = floorf(x);
      int x0 = (int)x0f;
      s_ix0[o] = x0;
      s_ix1[o] = min(x0 + 1, H - 1);
      s_lx[o] = x - x0f;
      s_vx[o] = v;
    }
  }
  __syncthreads();

  const int l = t & 63;
  const int w = t >> 6;  // 0..7

  // ---- roi-align: half-wave per cell, lane = 8 channels, packed f32 math --
  {
    const int hw = l >> 5;        // which cell of the pair
    const int c8 = (l & 31) * 8;  // channel offset
    for (int cb = w * 2; cb < 98; cb += 16) {
      const int cell = cb + hw;
      if (cell >= 98) continue;
      const int rr = (cell >= 49) ? 1 : 0;
      const int pos = cell - rr * 49;
      const int py = pos / 7, px = pos - (pos / 7) * 7;
      const ushort_t* clb = clb_[rr];
      const int W = W_[rr];
      float2v a01 = {0.f, 0.f}, a23 = {0.f, 0.f};
      float2v a45 = {0.f, 0.f}, a67 = {0.f, 0.f};
#pragma unroll
      for (int sy = 0; sy < 2; ++sy) {
        const int gy = rr * G_ + 2 * py + sy;
        const int iy0 = s_iy0[gy], iy1 = s_iy1[gy];
        const float ly = s_ly[gy], vy = s_vy[gy];
        const float hy = 1.0f - ly;
#pragma unroll
        for (int sx = 0; sx < 2; ++sx) {
          const int gx = rr * G_ + 2 * px + sx;
          const int ix0 = s_ix0[gx], ix1 = s_ix1[gx];
          const float lx = s_lx[gx], vx = s_vx[gx];
          const float hx = 1.0f - lx;
          const float vv = vy * vx;
          const float w00 = vv * hy * hx, w01 = vv * hy * lx;
          const float w10 = vv * ly * hx, w11 = vv * ly * lx;
          const uint4v u00 = *(const uint4v*)(clb + ((size_t)(iy0 * W + ix0) * 256 + c8));
          const uint4v u01 = *(const uint4v*)(clb + ((size_t)(iy0 * W + ix1) * 256 + c8));
          const uint4v u10 = *(const uint4v*)(clb + ((size_t)(iy1 * W + ix0) * 256 + c8));
          const uint4v u11 = *(const uint4v*)(clb + ((size_t)(iy1 * W + ix1) * 256 + c8));
          a01 += cvt2(u00[0]) * w00 + cvt2(u01[0]) * w01 +
                 cvt2(u10[0]) * w10 + cvt2(u11[0]) * w11;
          a23 += cvt2(u00[1]) * w00 + cvt2(u01[1]) * w01 +
                 cvt2(u10[1]) * w10 + cvt2(u11[1]) * w11;
          a45 += cvt2(u00[2]) * w00 + cvt2(u01[2]) * w01 +
                 cvt2(u10[2]) * w10 + cvt2(u11[2]) * w11;
          a67 += cvt2(u00[3]) * w00 + cvt2(u01[3]) * w01 +
                 cvt2(u10[3]) * w10 + cvt2(u11[3]) * w11;
        }
      }
      short8 pv;
      pv[0] = (short)f2bf(a01[0] * 0.25f);
      pv[1] = (short)f2bf(a01[1] * 0.25f);
      pv[2] = (short)f2bf(a23[0] * 0.25f);
      pv[3] = (short)f2bf(a23[1] * 0.25f);
      pv[4] = (short)f2bf(a45[0] * 0.25f);
      pv[5] = (short)f2bf(a45[1] * 0.25f);
      pv[6] = (short)f2bf(a67[0] * 0.25f);
      pv[7] = (short)f2bf(a67[1] * 0.25f);
      *(short8*)&s_pool[(rr * 50 + pos) * POOL_PITCH + c8] = pv;
    }
  }
  __syncthreads();  // pool + zero rows visible to all waves

  // ---- MFMA conv (R8 tiling): wave = 32 co x 4 pos-tiles ------------------
  const int ml = l & 31;
  const int quad = l >> 5;
  const int co_base = w * 32;

  const int pA = ml;
  const int pB = ml + 32;
  const int pyA = pA / 7, pxA = pA % 7;
  const int pyB = pB / 7, pxB = pB % 7;

  floatx16 acc[4];
#pragma unroll
  for (int a = 0; a < 4; ++a)
#pragma unroll
    for (int i = 0; i < 16; ++i) acc[a][i] = 0.f;

  const ushort_t* a0p = wr + (co_base + ml) * 16 + quad * 8;

  int kk = 0;
  for (int j = 0; j < 9; ++j) {
    const int dy = j / 3 - 1, dx = j % 3 - 1;
    int bnA, bnB;
    {
      const int ry = pyA + dy, rx = pxA + dx;
      const bool ok = (ry >= 0) & (ry < 7) & (rx >= 0) & (rx < 7);
      bnA = ok ? ry * 7 + rx : 49;
    }
    {
      const int ry = pyB + dy, rx = pxB + dx;
      const bool ok = (pB < 49) & (ry >= 0) & (ry < 7) & (rx >= 0) & (rx < 7);
      bnB = ok ? ry * 7 + rx : 49;
    }
    const int row0 = bnA, row1 = bnB, row2 = 50 + bnA, row3 = 50 + bnB;

#pragma unroll 4
    for (int kc = 0; kc < 16; ++kc, ++kk) {
      const short8 a0 = *(const short8*)(a0p + kk * 4096);
      const int cof = kc * 16 + quad * 8;
      const short8 b0 = *(const short8*)&s_pool[row0 * POOL_PITCH + cof];
      const short8 b1 = *(const short8*)&s_pool[row1 * POOL_PITCH + cof];
      const short8 b2 = *(const short8*)&s_pool[row2 * POOL_PITCH + cof];
      const short8 b3 = *(const short8*)&s_pool[row3 * POOL_PITCH + cof];
      acc[0] = __builtin_amdgcn_mfma_f32_32x32x16_bf16(a0, b0, acc[0], 0, 0, 0);
      acc[1] = __builtin_amdgcn_mfma_f32_32x32x16_bf16(a0, b1, acc[1], 0, 0, 0);
      acc[2] = __builtin_amdgcn_mfma_f32_32x32x16_bf16(a0, b2, acc[2], 0, 0, 0);
      acc[3] = __builtin_amdgcn_mfma_f32_32x32x16_bf16(a0, b3, acc[3], 0, 0, 0);
    }
  }
  __syncthreads();  // all pool reads done before h overwrites it

  // ---- epilogue: bias + relu -> h in LDS (fc-k order: [rr][co*49+pos]) ----
  ushort_t* h_lds = s_pool;
#pragma unroll
  for (int reg = 0; reg < 16; ++reg) {
    const int co = co_base + (reg & 3) + 8 * (reg >> 2) + 4 * quad;
    const float cb = conv_b[co];
    const int base = co * 49;
    h_lds[base + pA] = f2bf(fmaxf(acc[0][reg] + cb, 0.f));
    h_lds[12544 + base + pA] = f2bf(fmaxf(acc[2][reg] + cb, 0.f));
    if (pB < 49) {
      h_lds[base + pB] = f2bf(fmaxf(acc[1][reg] + cb, 0.f));
      h_lds[12544 + base + pB] = f2bf(fmaxf(acc[3][reg] + cb, 0.f));
    }
  }
  __syncthreads();

  // ---- FC(12544 -> 21) via MFMA 16x16x32, K-split across 8 waves ----------
  // A from fwb2 fragment order (coalesced 1 KB/wave); B cols 0/1 = roi 0/1.
  {
    const int n = l & 15;        // C/D col; valid cols 0,1
    const int kq = l >> 4;       // 0..3
    const ushort_t* ap0 = fwb + (n * 4 + kq) * 8;
    const ushort_t* ap1 = ap0 + 512;
    const ushort_t* bp = h_lds + (size_t)(l & 1) * 12544 + kq * 8;
    const int kb0 = w * 49;

    floatx4 fa0, fa1;
#pragma unroll
    for (int i = 0; i < 4; ++i) { fa0[i] = 0.f; fa1[i] = 0.f; }

    for (int it = 0; it < 49; ++it) {
      const int kb = kb0 + it;
      const short8 av0 = *(const short8*)(ap0 + kb * 1024);
      const short8 av1 = *(const short8*)(ap1 + kb * 1024);
      const short8 bv = *(const short8*)(bp + kb * 32);
      fa0 = __builtin_amdgcn_mfma_f32_16x16x32_bf16(av0, bv, fa0, 0, 0, 0);
      fa1 = __builtin_amdgcn_mfma_f32_16x16x32_bf16(av1, bv, fa1, 0, 0, 0);
    }
    // C/D layout: col = l&15, row = (l>>4)*4 + reg
    if (n < 2) {
      const int m4 = kq * 4;
#pragma unroll
      for (int reg = 0; reg < 4; ++reg) {
        const int cls0 = m4 + reg;
        const int cls1 = 16 + m4 + reg;
        s_fcred[(cls0 * 2 + n) * 8 + w] = fa0[reg];
        if (cls1 < NCLS) s_fcred[(cls1 * 2 + n) * 8 + w] = fa1[reg];
      }
    }
  }
  __syncthreads();
  if (t < 2 * NCLS) {
    const int cls = t >> 1;
    const int rr = t & 1;
    const float* pr = &s_fcred[(cls * 2 + rr) * 8];
    float s = pr[0] + pr[1] + pr[2] + pr[3] + pr[4] + pr[5] + pr[6] + pr[7];
    out[(size_t)(rid0 + rr) * NCLS + cls] = s + fc_b[cls];
  }
}

extern "C" void kernel_launch(void* const* d_in, const int* in_sizes, int n_in,
                              void* d_out, int out_size, void* d_ws,
                              size_t ws_size, hipStream_t stream) {
  const float* f3 = (const float*)d_in[0];
  const float* f4 = (const float*)d_in[1];
  const float* f5 = (const float*)d_in[2];
  const float* p3 = (const float*)d_in[3];
  const float* p4 = (const float*)d_in[4];
  const float* p5 = (const float*)d_in[5];
  const float* gt = (const float*)d_in[6];
  const float* cw = (const float*)d_in[7];
  const float* cb = (const float*)d_in[8];
  const float* fw = (const float*)d_in[9];
  const float* fb = (const float*)d_in[10];
  float* out = (float*)d_out;

  ushort_t* wsp = (ushort_t*)d_ws;
  ushort_t* wr = wsp;
  ushort_t* fwb = wsp + OFF_FWB;
  ushort_t* cl3 = wsp + OFF_CL3;
  ushort_t* cl4 = wsp + OFF_CL4;
  ushort_t* cl5 = wsp + OFF_CL5;

  prep_kernel<<<972, 256, 0, stream>>>(cw, fw, f3, f4, f5, p3, p4, p5, gt, wr,
                                       fwb, cl3, cl4, cl5, out);
  cls_head_kernel<<<NROI_TOT / 2, 512, 0, stream>>>(cl3, cl4, cl5, p3, p4, p5,
                                                    wr, cb, fwb, fb, out);
}